// Round 5
// baseline (719.160 us; speedup 1.0000x reference)
//
#include <hip/hip_runtime.h>
#include <hip/hip_bf16.h>
#include <stdint.h>

#define B_ 128
#define T_ 255
#define N_ 256
#define H_ 256

typedef _Float16 f16;
typedef _Float16 f16x2 __attribute__((ext_vector_type(2)));
typedef _Float16 f16x8 __attribute__((ext_vector_type(8)));
typedef float f32x4 __attribute__((ext_vector_type(4)));

static __device__ __forceinline__ float fdot2(uint32_t h, uint32_t u, float acc) {
#if __has_builtin(__builtin_amdgcn_fdot2)
  return __builtin_amdgcn_fdot2(__builtin_bit_cast(f16x2, h),
                                __builtin_bit_cast(f16x2, u), acc, false);
#else
  f16x2 a = __builtin_bit_cast(f16x2, h);
  f16x2 b = __builtin_bit_cast(f16x2, u);
  return acc + (float)a.x * (float)b.x + (float)a.y * (float)b.y;
#endif
}

// ---------------- K0: pack W_lstm (transposed) and U_lstm (k-pair packed) to f16
__global__ __launch_bounds__(256) void k0_pack(const float* __restrict__ Wl,
                                               const float* __restrict__ Ul,
                                               uint32_t* __restrict__ u_packed,
                                               f16* __restrict__ wt) {
  int idx = blockIdx.x * 256 + threadIdx.x;
  if (idx < 256 * 1024) {              // wt[n][k] = Wl[k][n]
    int n = idx >> 8, k = idx & 255;
    wt[n * 256 + k] = (f16)Wl[k * 1024 + n];
  }
  if (idx < 128 * 1024) {              // u_packed[p][c] = (U[2p][c], U[2p+1][c])
    int p = idx >> 10, c = idx & 1023;
    f16x2 v;
    v.x = (f16)Ul[(2 * p) * 1024 + c];
    v.y = (f16)Ul[(2 * p + 1) * 1024 + c];
    u_packed[idx] = __builtin_bit_cast(uint32_t, v);
  }
}

// ---------------- K1: alpha[b][n] = softmax_n( sum_t X[b,t,n] * Wa[512+t] )
__global__ __launch_bounds__(256) void k1_alpha(const float* __restrict__ X,
                                                const float* __restrict__ Wa,
                                                float* __restrict__ alpha) {
  int b = blockIdx.x, n = threadIdx.x;
  const float* xb = X + b * (T_ * N_) + n;
  float a0 = 0.f, a1 = 0.f, a2 = 0.f, a3 = 0.f;
  int t = 0;
  for (; t + 4 <= T_; t += 4) {
    a0 += xb[(t + 0) * N_] * Wa[512 + t + 0];
    a1 += xb[(t + 1) * N_] * Wa[512 + t + 1];
    a2 += xb[(t + 2) * N_] * Wa[512 + t + 2];
    a3 += xb[(t + 3) * N_] * Wa[512 + t + 3];
  }
  for (; t < T_; ++t) a0 += xb[t * N_] * Wa[512 + t];
  float e = (a0 + a1) + (a2 + a3);

  __shared__ float red[4];
  float m = e;
  for (int off = 32; off > 0; off >>= 1) m = fmaxf(m, __shfl_xor(m, off));
  int wid = n >> 6;
  if ((n & 63) == 0) red[wid] = m;
  __syncthreads();
  m = fmaxf(fmaxf(red[0], red[1]), fmaxf(red[2], red[3]));
  float ex = __expf(e - m);
  float s = ex;
  for (int off = 32; off > 0; off >>= 1) s += __shfl_xor(s, off);
  __syncthreads();
  if ((n & 63) == 0) red[wid] = s;
  __syncthreads();
  s = (red[0] + red[1]) + (red[2] + red[3]);
  alpha[b * N_ + n] = ex / s;
}

// ---------------- K2: X_tilde = alpha (broadcast over t) * X   (exact fp32)
__global__ __launch_bounds__(256) void k2_xtilde(const float4* __restrict__ X4,
                                                 const float* __restrict__ alpha,
                                                 float4* __restrict__ out4) {
  int i = blockIdx.x * 256 + threadIdx.x;  // over B*T*64 float4s
  if (i < B_ * T_ * 64) {
    int n4 = i & 63;
    int bt = i >> 6;
    int b = bt / T_;
    const float4* A4 = (const float4*)alpha;
    float4 x = X4[i], al = A4[b * 64 + n4];
    float4 r;
    r.x = x.x * al.x; r.y = x.y * al.y; r.z = x.z * al.z; r.w = x.w * al.w;
    out4[i] = r;
  }
}

// ---------------- K3: XW = X_tilde @ W_lstm + b_lstm  -> f16 (32640 x 1024)
#define LDA 40  // f16 row stride in LDS (16B-aligned rows, bank-spread)
__global__ __launch_bounds__(256, 2) void k3_gemm(const float* __restrict__ A,
                                                  const f16* __restrict__ Bt,
                                                  const float* __restrict__ bias,
                                                  f16* __restrict__ Cw) {
  __shared__ f16 As[128 * LDA];
  __shared__ f16 Bs[128 * LDA];
  int tid = threadIdx.x;
  int mt = blockIdx.x;  // 0..254
  int nt = blockIdx.y;  // 0..7
  int lane = tid & 63, wid = tid >> 6;
  int wm = (wid >> 1) * 64, wn = (wid & 1) * 64;
  f32x4 acc[4][4] = {};

  for (int k0 = 0; k0 < 256; k0 += 32) {
    __syncthreads();
#pragma unroll
    for (int it = 0; it < 4; ++it) {  // A: 128 rows x 32 f32 -> f16
      int idx = tid + it * 256;
      int r = idx >> 3, q = idx & 7;
      float4 v = *(const float4*)(A + (mt * 128 + r) * 256 + k0 + q * 4);
      f16x2 p0, p1;
      p0.x = (f16)v.x; p0.y = (f16)v.y; p1.x = (f16)v.z; p1.y = (f16)v.w;
      uint2 w;
      w.x = __builtin_bit_cast(uint32_t, p0);
      w.y = __builtin_bit_cast(uint32_t, p1);
      *(uint2*)(&As[r * LDA + q * 4]) = w;
    }
#pragma unroll
    for (int it = 0; it < 2; ++it) {  // B (already transposed): 128 rows x 32 f16
      int idx = tid + it * 256;
      int r = idx >> 2, q = idx & 3;
      uint4 v = *(const uint4*)(Bt + (nt * 128 + r) * 256 + k0 + q * 8);
      *(uint4*)(&Bs[r * LDA + q * 8]) = v;
    }
    __syncthreads();
    int kb = (lane >> 4) * 8;
    f16x8 af[4], bf[4];
#pragma unroll
    for (int i = 0; i < 4; ++i)
      af[i] = *(const f16x8*)(&As[(wm + i * 16 + (lane & 15)) * LDA + kb]);
#pragma unroll
    for (int j = 0; j < 4; ++j)
      bf[j] = *(const f16x8*)(&Bs[(wn + j * 16 + (lane & 15)) * LDA + kb]);
#pragma unroll
    for (int i = 0; i < 4; ++i)
#pragma unroll
      for (int j = 0; j < 4; ++j)
        acc[i][j] = __builtin_amdgcn_mfma_f32_16x16x32_f16(af[i], bf[j], acc[i][j], 0, 0, 0);
  }
  int colL = wn + (lane & 15);
  int rowB = wm + (lane >> 4) * 4;
#pragma unroll
  for (int j = 0; j < 4; ++j) {
    int ng = nt * 128 + colL + j * 16;
    float bv = bias[ng];
#pragma unroll
    for (int i = 0; i < 4; ++i)
#pragma unroll
      for (int r = 0; r < 4; ++r) {
        int mg = mt * 128 + rowB + i * 16 + r;
        Cw[mg * 1024 + ng] = (f16)(acc[i][j][r] + bv);
      }
  }
}

// ---------------- K4: sequential LSTM recurrence, one block per batch.
// 512 threads, 2 z-columns per thread. U k-pairs [0,96) are loaded by
// ASM VOLATILE global_load_dwordx2 into 96 NAMED uint64 scalars (192 VGPRs).
// Rounds 1-4 proved the compiler demotes any large local ARRAY and re-reads
// U from L2 every step (~5000 cyc/step); volatile asm outputs cannot be
// rematerialized or demoted, so U residency is now structural. Pairs
// [96,128) live in LDS (128 KB as 16 uint4 groups). Every in-loop use of
// the asm values depends on post-barrier LDS h-reads, so nothing can be
// hoisted above the explicit s_waitcnt vmcnt(0).
#define UL(p) uint64_t u##p; \
  asm volatile("global_load_dwordx2 %0, %1, off" : "=v"(u##p) : "v"(up2 + (p) * 512 + tid));

#define DOTP(p, hreg, A0, A1) { uint2 uu = __builtin_bit_cast(uint2, u##p); \
  A0 = fdot2(hreg, uu.x, A0); A1 = fdot2(hreg, uu.y, A1); }

#define QBLK(q, p0, p1, p2, p3) { uint4 hh = h4[q]; \
  DOTP(p0, hh.x, z0a, z1a) DOTP(p1, hh.y, z0b, z1b) \
  DOTP(p2, hh.z, z0a, z1a) DOTP(p3, hh.w, z0b, z1b) }

#define QLDS(q) { uint4 hh = h4[q]; int g = 2 * ((q) - 24); \
  uint4 ua = u_lds4[g * 512 + tid]; uint4 ub = u_lds4[(g + 1) * 512 + tid]; \
  z0a = fdot2(hh.x, ua.x, z0a); z1a = fdot2(hh.x, ua.y, z1a); \
  z0b = fdot2(hh.y, ua.z, z0b); z1b = fdot2(hh.y, ua.w, z1b); \
  z0a = fdot2(hh.z, ub.x, z0a); z1a = fdot2(hh.z, ub.y, z1a); \
  z0b = fdot2(hh.w, ub.z, z0b); z1b = fdot2(hh.w, ub.w, z1b); }

__global__ __launch_bounds__(512)
__attribute__((amdgpu_waves_per_eu(1, 2)))
void k4_recur(const float* __restrict__ X,
              const uint32_t* __restrict__ u_packed,
              const uint32_t* __restrict__ xw2,
              float* __restrict__ Xenc) {
  __shared__ __align__(16) uint4 u_lds4[16 * 512];  // 128 KB: pairs 96..127
  __shared__ __align__(16) f16 h_lds[256];          // 512 B
  __shared__ __align__(16) float z_lds[1024];       // 4 KB
  int tid = threadIdx.x, b = blockIdx.x;
  const uint2* up2 = (const uint2*)u_packed;

  UL(0)  UL(1)  UL(2)  UL(3)  UL(4)  UL(5)  UL(6)  UL(7)
  UL(8)  UL(9)  UL(10) UL(11) UL(12) UL(13) UL(14) UL(15)
  UL(16) UL(17) UL(18) UL(19) UL(20) UL(21) UL(22) UL(23)
  UL(24) UL(25) UL(26) UL(27) UL(28) UL(29) UL(30) UL(31)
  UL(32) UL(33) UL(34) UL(35) UL(36) UL(37) UL(38) UL(39)
  UL(40) UL(41) UL(42) UL(43) UL(44) UL(45) UL(46) UL(47)
  UL(48) UL(49) UL(50) UL(51) UL(52) UL(53) UL(54) UL(55)
  UL(56) UL(57) UL(58) UL(59) UL(60) UL(61) UL(62) UL(63)
  UL(64) UL(65) UL(66) UL(67) UL(68) UL(69) UL(70) UL(71)
  UL(72) UL(73) UL(74) UL(75) UL(76) UL(77) UL(78) UL(79)
  UL(80) UL(81) UL(82) UL(83) UL(84) UL(85) UL(86) UL(87)
  UL(88) UL(89) UL(90) UL(91) UL(92) UL(93) UL(94) UL(95)

  // LDS staging: group g holds pairs (96+2g, 97+2g), cols (2tid, 2tid+1)
#pragma unroll
  for (int g = 0; g < 16; ++g) {
    uint2 a = up2[(96 + 2 * g) * 512 + tid];
    uint2 c = up2[(97 + 2 * g) * 512 + tid];
    uint4 v;
    v.x = a.x; v.y = a.y; v.z = c.x; v.w = c.y;
    u_lds4[g * 512 + tid] = v;
  }
  float x00 = X[b * (T_ * N_)];
  float c_st = x00;
  if (tid < 256) h_lds[tid] = (f16)x00;
  asm volatile("s_waitcnt vmcnt(0)" ::: "memory");
  __syncthreads();

  const uint32_t* xwb = xw2 + (size_t)b * T_ * 512;
  float* encb = Xenc + (size_t)b * T_ * N_;
  const uint4* h4 = (const uint4*)h_lds;

  uint32_t xwv = xwb[tid];
  for (int t = 0; t < T_; ++t) {
    uint32_t xw_nxt = 0;
    if (t + 1 < T_) xw_nxt = xwb[(t + 1) * 512 + tid];

    float z0a, z1a;
    {
      f16x2 xp = __builtin_bit_cast(f16x2, xwv);
      z0a = (float)xp.x;
      z1a = (float)xp.y;
    }
    float z0b = 0.f, z1b = 0.f;

    QBLK(0,  0,  1,  2,  3)   QBLK(1,  4,  5,  6,  7)
    QBLK(2,  8,  9,  10, 11)  QBLK(3,  12, 13, 14, 15)
    QBLK(4,  16, 17, 18, 19)  QBLK(5,  20, 21, 22, 23)
    QBLK(6,  24, 25, 26, 27)  QBLK(7,  28, 29, 30, 31)
    QBLK(8,  32, 33, 34, 35)  QBLK(9,  36, 37, 38, 39)
    QBLK(10, 40, 41, 42, 43)  QBLK(11, 44, 45, 46, 47)
    QBLK(12, 48, 49, 50, 51)  QBLK(13, 52, 53, 54, 55)
    QBLK(14, 56, 57, 58, 59)  QBLK(15, 60, 61, 62, 63)
    QBLK(16, 64, 65, 66, 67)  QBLK(17, 68, 69, 70, 71)
    QBLK(18, 72, 73, 74, 75)  QBLK(19, 76, 77, 78, 79)
    QBLK(20, 80, 81, 82, 83)  QBLK(21, 84, 85, 86, 87)
    QBLK(22, 88, 89, 90, 91)  QBLK(23, 92, 93, 94, 95)

    QLDS(24) QLDS(25) QLDS(26) QLDS(27)
    QLDS(28) QLDS(29) QLDS(30) QLDS(31)

    float2 zz;
    zz.x = z0a + z0b;
    zz.y = z1a + z1b;
    *(float2*)&z_lds[2 * tid] = zz;
    __syncthreads();
    if (tid < 256) {
      float zi = z_lds[tid], zf = z_lds[256 + tid];
      float zg = z_lds[512 + tid], zo = z_lds[768 + tid];
      float ig = 1.f / (1.f + __expf(-zi));
      float fg = 1.f / (1.f + __expf(-zf));
      float gg = 1.f - 2.f / (1.f + __expf(2.f * zg));
      float og = 1.f / (1.f + __expf(-zo));
      c_st = fg * c_st + ig * gg;
      float hv = og * (1.f - 2.f / (1.f + __expf(2.f * c_st)));
      encb[t * 256 + tid] = hv;
      h_lds[tid] = (f16)hv;
    }
    __syncthreads();
    xwv = xw_nxt;
  }
}

extern "C" void kernel_launch(void* const* d_in, const int* in_sizes, int n_in,
                              void* d_out, int out_size, void* d_ws, size_t ws_size,
                              hipStream_t stream) {
  const float* X = (const float*)d_in[0];
  const float* Wa = (const float*)d_in[1];
  const float* Wl = (const float*)d_in[3];
  const float* Ul = (const float*)d_in[4];
  const float* bl = (const float*)d_in[5];
  float* out = (float*)d_out;
  uint8_t* ws = (uint8_t*)d_ws;

  float* alpha = (float*)ws;                          // 131072 B
  uint32_t* u_packed = (uint32_t*)(ws + 131072);      // 524288 B
  f16* wt = (f16*)(ws + 655360);                      // 524288 B
  f16* xw = (f16*)(ws + 1179648);                     // 66846720 B (~68 MB total)

  k0_pack<<<1024, 256, 0, stream>>>(Wl, Ul, u_packed, wt);
  k1_alpha<<<128, 256, 0, stream>>>(X, Wa, alpha);
  k2_xtilde<<<8160, 256, 0, stream>>>((const float4*)X, alpha, (float4*)out);
  dim3 g3(255, 8);
  k3_gemm<<<g3, 256, 0, stream>>>(out, wt, bl, xw);
  k4_recur<<<128, 512, 0, stream>>>(X, u_packed, (const uint32_t*)xw,
                                    out + 8355840);
}

// Round 6
// 682.046 us; speedup vs baseline: 1.0544x; 1.0544x over previous
//
#include <hip/hip_runtime.h>
#include <hip/hip_bf16.h>
#include <stdint.h>

#define B_ 128
#define T_ 255
#define N_ 256
#define H_ 256

typedef _Float16 f16;
typedef _Float16 f16x2 __attribute__((ext_vector_type(2)));
typedef _Float16 f16x8 __attribute__((ext_vector_type(8)));
typedef float f32x4 __attribute__((ext_vector_type(4)));

static __device__ __forceinline__ float fdot2(uint32_t h, uint32_t u, float acc) {
#if __has_builtin(__builtin_amdgcn_fdot2)
  return __builtin_amdgcn_fdot2(__builtin_bit_cast(f16x2, h),
                                __builtin_bit_cast(f16x2, u), acc, false);
#else
  f16x2 a = __builtin_bit_cast(f16x2, h);
  f16x2 b = __builtin_bit_cast(f16x2, u);
  return acc + (float)a.x * (float)b.x + (float)a.y * (float)b.y;
#endif
}

// ---------------- K0: pack W_lstm (transposed) and U_lstm (k-pair packed) to f16
__global__ __launch_bounds__(256) void k0_pack(const float* __restrict__ Wl,
                                               const float* __restrict__ Ul,
                                               uint32_t* __restrict__ u_packed,
                                               f16* __restrict__ wt) {
  int idx = blockIdx.x * 256 + threadIdx.x;
  if (idx < 256 * 1024) {              // wt[n][k] = Wl[k][n]
    int n = idx >> 8, k = idx & 255;
    wt[n * 256 + k] = (f16)Wl[k * 1024 + n];
  }
  if (idx < 128 * 1024) {              // u_packed[p][c] = (U[2p][c], U[2p+1][c])
    int p = idx >> 10, c = idx & 1023;
    f16x2 v;
    v.x = (f16)Ul[(2 * p) * 1024 + c];
    v.y = (f16)Ul[(2 * p + 1) * 1024 + c];
    u_packed[idx] = __builtin_bit_cast(uint32_t, v);
  }
}

// ---------------- K1: alpha[b][n] = softmax_n( sum_t X[b,t,n] * Wa[512+t] )
__global__ __launch_bounds__(256) void k1_alpha(const float* __restrict__ X,
                                                const float* __restrict__ Wa,
                                                float* __restrict__ alpha) {
  int b = blockIdx.x, n = threadIdx.x;
  const float* xb = X + b * (T_ * N_) + n;
  float a0 = 0.f, a1 = 0.f, a2 = 0.f, a3 = 0.f;
  int t = 0;
  for (; t + 4 <= T_; t += 4) {
    a0 += xb[(t + 0) * N_] * Wa[512 + t + 0];
    a1 += xb[(t + 1) * N_] * Wa[512 + t + 1];
    a2 += xb[(t + 2) * N_] * Wa[512 + t + 2];
    a3 += xb[(t + 3) * N_] * Wa[512 + t + 3];
  }
  for (; t < T_; ++t) a0 += xb[t * N_] * Wa[512 + t];
  float e = (a0 + a1) + (a2 + a3);

  __shared__ float red[4];
  float m = e;
  for (int off = 32; off > 0; off >>= 1) m = fmaxf(m, __shfl_xor(m, off));
  int wid = n >> 6;
  if ((n & 63) == 0) red[wid] = m;
  __syncthreads();
  m = fmaxf(fmaxf(red[0], red[1]), fmaxf(red[2], red[3]));
  float ex = __expf(e - m);
  float s = ex;
  for (int off = 32; off > 0; off >>= 1) s += __shfl_xor(s, off);
  __syncthreads();
  if ((n & 63) == 0) red[wid] = s;
  __syncthreads();
  s = (red[0] + red[1]) + (red[2] + red[3]);
  alpha[b * N_ + n] = ex / s;
}

// ---------------- K2: X_tilde = alpha (broadcast over t) * X   (exact fp32)
__global__ __launch_bounds__(256) void k2_xtilde(const float4* __restrict__ X4,
                                                 const float* __restrict__ alpha,
                                                 float4* __restrict__ out4) {
  int i = blockIdx.x * 256 + threadIdx.x;  // over B*T*64 float4s
  if (i < B_ * T_ * 64) {
    int n4 = i & 63;
    int bt = i >> 6;
    int b = bt / T_;
    const float4* A4 = (const float4*)alpha;
    float4 x = X4[i], al = A4[b * 64 + n4];
    float4 r;
    r.x = x.x * al.x; r.y = x.y * al.y; r.z = x.z * al.z; r.w = x.w * al.w;
    out4[i] = r;
  }
}

// ---------------- K3: XW = X_tilde @ W_lstm + b_lstm  -> f16 (32640 x 1024)
#define LDA 40  // f16 row stride in LDS (16B-aligned rows, bank-spread)
__global__ __launch_bounds__(256, 2) void k3_gemm(const float* __restrict__ A,
                                                  const f16* __restrict__ Bt,
                                                  const float* __restrict__ bias,
                                                  f16* __restrict__ Cw) {
  __shared__ f16 As[128 * LDA];
  __shared__ f16 Bs[128 * LDA];
  int tid = threadIdx.x;
  int mt = blockIdx.x;  // 0..254
  int nt = blockIdx.y;  // 0..7
  int lane = tid & 63, wid = tid >> 6;
  int wm = (wid >> 1) * 64, wn = (wid & 1) * 64;
  f32x4 acc[4][4] = {};

  for (int k0 = 0; k0 < 256; k0 += 32) {
    __syncthreads();
#pragma unroll
    for (int it = 0; it < 4; ++it) {  // A: 128 rows x 32 f32 -> f16
      int idx = tid + it * 256;
      int r = idx >> 3, q = idx & 7;
      float4 v = *(const float4*)(A + (mt * 128 + r) * 256 + k0 + q * 4);
      f16x2 p0, p1;
      p0.x = (f16)v.x; p0.y = (f16)v.y; p1.x = (f16)v.z; p1.y = (f16)v.w;
      uint2 w;
      w.x = __builtin_bit_cast(uint32_t, p0);
      w.y = __builtin_bit_cast(uint32_t, p1);
      *(uint2*)(&As[r * LDA + q * 4]) = w;
    }
#pragma unroll
    for (int it = 0; it < 2; ++it) {  // B (already transposed): 128 rows x 32 f16
      int idx = tid + it * 256;
      int r = idx >> 2, q = idx & 3;
      uint4 v = *(const uint4*)(Bt + (nt * 128 + r) * 256 + k0 + q * 8);
      *(uint4*)(&Bs[r * LDA + q * 8]) = v;
    }
    __syncthreads();
    int kb = (lane >> 4) * 8;
    f16x8 af[4], bf[4];
#pragma unroll
    for (int i = 0; i < 4; ++i)
      af[i] = *(const f16x8*)(&As[(wm + i * 16 + (lane & 15)) * LDA + kb]);
#pragma unroll
    for (int j = 0; j < 4; ++j)
      bf[j] = *(const f16x8*)(&Bs[(wn + j * 16 + (lane & 15)) * LDA + kb]);
#pragma unroll
    for (int i = 0; i < 4; ++i)
#pragma unroll
      for (int j = 0; j < 4; ++j)
        acc[i][j] = __builtin_amdgcn_mfma_f32_16x16x32_f16(af[i], bf[j], acc[i][j], 0, 0, 0);
  }
  int colL = wn + (lane & 15);
  int rowB = wm + (lane >> 4) * 4;
#pragma unroll
  for (int j = 0; j < 4; ++j) {
    int ng = nt * 128 + colL + j * 16;
    float bv = bias[ng];
#pragma unroll
    for (int i = 0; i < 4; ++i)
#pragma unroll
      for (int r = 0; r < 4; ++r) {
        int mg = mt * 128 + rowB + i * 16 + r;
        Cw[mg * 1024 + ng] = (f16)(acc[i][j][r] + bv);
      }
  }
}

// ---------------- K4: sequential LSTM recurrence, one block per batch.
// 512 threads, 2 z-columns per thread. U k-pairs [0,96) pinned via asm
// volatile loads (r5: survives, no per-step memory reload — FETCH stayed at
// the xw stream). r5 diagnosis: 384 ds_read_b128/CU/step (h re-broadcast 32x
// per thread + U-LDS) saturated the per-CU LDS pipe (~3100 cyc) while VALU
// idled at 23%. Fix: h is read ONCE per wave per step (ds_read_b64; lane L
// holds h-pairs 2L,2L+1) and pairs are extracted with v_readlane into SGPRs,
// consumed directly by v_dot2 (VALU pipe, legal 1-SGPR operand). h-LDS
// traffic: 256 -> 8 insts/CU/step.
#define UL(p) uint64_t u##p; \
  asm volatile("global_load_dwordx2 %0, %1, off" : "=v"(u##p) : "v"(up2 + (p) * 512 + tid));

#define DOTP(p, hreg, A0, A1) { uint2 uu = __builtin_bit_cast(uint2, u##p); \
  A0 = fdot2(hreg, uu.x, A0); A1 = fdot2(hreg, uu.y, A1); }

#define RL4(g) \
  uint32_t s0 = (uint32_t)__builtin_amdgcn_readlane((int)hv0, 2 * (g)); \
  uint32_t s1 = (uint32_t)__builtin_amdgcn_readlane((int)hv1, 2 * (g)); \
  uint32_t s2 = (uint32_t)__builtin_amdgcn_readlane((int)hv0, 2 * (g) + 1); \
  uint32_t s3 = (uint32_t)__builtin_amdgcn_readlane((int)hv1, 2 * (g) + 1);

#define QBLK(g, p0, p1, p2, p3) { RL4(g) \
  DOTP(p0, s0, z0a, z1a) DOTP(p1, s1, z0b, z1b) \
  DOTP(p2, s2, z0a, z1a) DOTP(p3, s3, z0b, z1b) }

#define QLDS(g) { RL4(g) int gg = 2 * ((g) - 24); \
  uint4 ua = u_lds4[gg * 512 + tid]; uint4 ub = u_lds4[(gg + 1) * 512 + tid]; \
  z0a = fdot2(s0, ua.x, z0a); z1a = fdot2(s0, ua.y, z1a); \
  z0b = fdot2(s1, ua.z, z0b); z1b = fdot2(s1, ua.w, z1b); \
  z0a = fdot2(s2, ub.x, z0a); z1a = fdot2(s2, ub.y, z1a); \
  z0b = fdot2(s3, ub.z, z0b); z1b = fdot2(s3, ub.w, z1b); }

__global__ __launch_bounds__(512)
__attribute__((amdgpu_waves_per_eu(1, 2)))
void k4_recur(const float* __restrict__ X,
              const uint32_t* __restrict__ u_packed,
              const uint32_t* __restrict__ xw2,
              float* __restrict__ Xenc) {
  __shared__ __align__(16) uint4 u_lds4[16 * 512];  // 128 KB: pairs 96..127
  __shared__ __align__(16) f16 h_lds[256];          // 512 B
  __shared__ __align__(16) float z_lds[1024];       // 4 KB
  int tid = threadIdx.x, b = blockIdx.x;
  int lane = tid & 63;
  const uint2* up2 = (const uint2*)u_packed;

  UL(0)  UL(1)  UL(2)  UL(3)  UL(4)  UL(5)  UL(6)  UL(7)
  UL(8)  UL(9)  UL(10) UL(11) UL(12) UL(13) UL(14) UL(15)
  UL(16) UL(17) UL(18) UL(19) UL(20) UL(21) UL(22) UL(23)
  UL(24) UL(25) UL(26) UL(27) UL(28) UL(29) UL(30) UL(31)
  UL(32) UL(33) UL(34) UL(35) UL(36) UL(37) UL(38) UL(39)
  UL(40) UL(41) UL(42) UL(43) UL(44) UL(45) UL(46) UL(47)
  UL(48) UL(49) UL(50) UL(51) UL(52) UL(53) UL(54) UL(55)
  UL(56) UL(57) UL(58) UL(59) UL(60) UL(61) UL(62) UL(63)
  UL(64) UL(65) UL(66) UL(67) UL(68) UL(69) UL(70) UL(71)
  UL(72) UL(73) UL(74) UL(75) UL(76) UL(77) UL(78) UL(79)
  UL(80) UL(81) UL(82) UL(83) UL(84) UL(85) UL(86) UL(87)
  UL(88) UL(89) UL(90) UL(91) UL(92) UL(93) UL(94) UL(95)

  // LDS staging: group g holds pairs (96+2g, 97+2g), cols (2tid, 2tid+1)
#pragma unroll
  for (int g = 0; g < 16; ++g) {
    uint2 a = up2[(96 + 2 * g) * 512 + tid];
    uint2 c = up2[(97 + 2 * g) * 512 + tid];
    uint4 v;
    v.x = a.x; v.y = a.y; v.z = c.x; v.w = c.y;
    u_lds4[g * 512 + tid] = v;
  }
  float x00 = X[b * (T_ * N_)];
  float c_st = x00;
  if (tid < 256) h_lds[tid] = (f16)x00;
  asm volatile("s_waitcnt vmcnt(0)" ::: "memory");
  __syncthreads();

  const uint32_t* xwb = xw2 + (size_t)b * T_ * 512;
  float* encb = Xenc + (size_t)b * T_ * N_;

  uint32_t xwv = xwb[tid];
  for (int t = 0; t < T_; ++t) {
    uint32_t xw_nxt = 0;
    if (t + 1 < T_) xw_nxt = xwb[(t + 1) * 512 + tid];

    // one b64 per wave: lane L holds h-pairs 2L (hv0) and 2L+1 (hv1)
    uint32_t hv0, hv1;
    {
      uint2 hh = *(const uint2*)&h_lds[4 * lane];
      hv0 = hh.x;
      hv1 = hh.y;
    }

    float z0a, z1a;
    {
      f16x2 xp = __builtin_bit_cast(f16x2, xwv);
      z0a = (float)xp.x;
      z1a = (float)xp.y;
    }
    float z0b = 0.f, z1b = 0.f;

    QBLK(0,  0,  1,  2,  3)   QBLK(1,  4,  5,  6,  7)
    QBLK(2,  8,  9,  10, 11)  QBLK(3,  12, 13, 14, 15)
    QBLK(4,  16, 17, 18, 19)  QBLK(5,  20, 21, 22, 23)
    QBLK(6,  24, 25, 26, 27)  QBLK(7,  28, 29, 30, 31)
    QBLK(8,  32, 33, 34, 35)  QBLK(9,  36, 37, 38, 39)
    QBLK(10, 40, 41, 42, 43)  QBLK(11, 44, 45, 46, 47)
    QBLK(12, 48, 49, 50, 51)  QBLK(13, 52, 53, 54, 55)
    QBLK(14, 56, 57, 58, 59)  QBLK(15, 60, 61, 62, 63)
    QBLK(16, 64, 65, 66, 67)  QBLK(17, 68, 69, 70, 71)
    QBLK(18, 72, 73, 74, 75)  QBLK(19, 76, 77, 78, 79)
    QBLK(20, 80, 81, 82, 83)  QBLK(21, 84, 85, 86, 87)
    QBLK(22, 88, 89, 90, 91)  QBLK(23, 92, 93, 94, 95)

    QLDS(24) QLDS(25) QLDS(26) QLDS(27)
    QLDS(28) QLDS(29) QLDS(30) QLDS(31)

    float2 zz;
    zz.x = z0a + z0b;
    zz.y = z1a + z1b;
    *(float2*)&z_lds[2 * tid] = zz;
    __syncthreads();
    if (tid < 256) {
      float zi = z_lds[tid], zf = z_lds[256 + tid];
      float zg = z_lds[512 + tid], zo = z_lds[768 + tid];
      float ig = 1.f / (1.f + __expf(-zi));
      float fg = 1.f / (1.f + __expf(-zf));
      float gg = 1.f - 2.f / (1.f + __expf(2.f * zg));
      float og = 1.f / (1.f + __expf(-zo));
      c_st = fg * c_st + ig * gg;
      float hv = og * (1.f - 2.f / (1.f + __expf(2.f * c_st)));
      encb[t * 256 + tid] = hv;
      h_lds[tid] = (f16)hv;
    }
    __syncthreads();
    xwv = xw_nxt;
  }
}

extern "C" void kernel_launch(void* const* d_in, const int* in_sizes, int n_in,
                              void* d_out, int out_size, void* d_ws, size_t ws_size,
                              hipStream_t stream) {
  const float* X = (const float*)d_in[0];
  const float* Wa = (const float*)d_in[1];
  const float* Wl = (const float*)d_in[3];
  const float* Ul = (const float*)d_in[4];
  const float* bl = (const float*)d_in[5];
  float* out = (float*)d_out;
  uint8_t* ws = (uint8_t*)d_ws;

  float* alpha = (float*)ws;                          // 131072 B
  uint32_t* u_packed = (uint32_t*)(ws + 131072);      // 524288 B
  f16* wt = (f16*)(ws + 655360);                      // 524288 B
  f16* xw = (f16*)(ws + 1179648);                     // 66846720 B (~68 MB total)

  k0_pack<<<1024, 256, 0, stream>>>(Wl, Ul, u_packed, wt);
  k1_alpha<<<128, 256, 0, stream>>>(X, Wa, alpha);
  k2_xtilde<<<8160, 256, 0, stream>>>((const float4*)X, alpha, (float4*)out);
  dim3 g3(255, 8);
  k3_gemm<<<g3, 256, 0, stream>>>(out, wt, bl, xw);
  k4_recur<<<128, 512, 0, stream>>>(X, u_packed, (const uint32_t*)xw,
                                    out + 8355840);
}